// Round 1
// baseline (115.722 us; speedup 1.0000x reference)
//
#include <hip/hip_runtime.h>
#include <hip/hip_bf16.h>
#include <math.h>

#define IMG_H 1024
#define IMG_W 1024
#define NBATCH 32

// One block per (batch,row). 256 threads, each handles 4 consecutive pixels.
__global__ __launch_bounds__(256) void keypoint_kernel(
    const float* __restrict__ in, float* __restrict__ kp_out,
    float* __restrict__ conf_out) {
  const int row = blockIdx.x;          // 0 .. NBATCH*IMG_H-1
  const int b = row >> 10;             // /IMG_H
  const int y = row & (IMG_H - 1);
  const size_t img_off = (size_t)b * IMG_H * IMG_W;
  const float* img = in + img_off;

  const int x0 = threadIdx.x << 2;     // 4 px per thread
  const float* rc = img + (size_t)y * IMG_W + x0;

  // center row
  const float4 c = *(const float4*)rc;
  float vm1 = (x0 > 0) ? rc[-1] : -INFINITY;
  float v0 = c.x, v1 = c.y, v2 = c.z, v3 = c.w;
  float v4 = (x0 + 4 < IMG_W) ? rc[4] : -INFINITY;

  // row above
  if (y > 0) {
    const float* ru = rc - IMG_W;
    const float4 t = *(const float4*)ru;
    if (x0 > 0) vm1 = fmaxf(vm1, ru[-1]);
    v0 = fmaxf(v0, t.x); v1 = fmaxf(v1, t.y);
    v2 = fmaxf(v2, t.z); v3 = fmaxf(v3, t.w);
    if (x0 + 4 < IMG_W) v4 = fmaxf(v4, ru[4]);
  }
  // row below
  if (y < IMG_H - 1) {
    const float* rd = rc + IMG_W;
    const float4 t = *(const float4*)rd;
    if (x0 > 0) vm1 = fmaxf(vm1, rd[-1]);
    v0 = fmaxf(v0, t.x); v1 = fmaxf(v1, t.y);
    v2 = fmaxf(v2, t.z); v3 = fmaxf(v3, t.w);
    if (x0 + 4 < IMG_W) v4 = fmaxf(v4, rd[4]);
  }

  // horizontal 3-max -> pooled
  const float p0 = fmaxf(fmaxf(vm1, v0), v1);
  const float p1 = fmaxf(fmaxf(v0, v1), v2);
  const float p2 = fmaxf(fmaxf(v1, v2), v3);
  const float p3 = fmaxf(fmaxf(v2, v3), v4);

  const float THR = 0.3f;
  const bool k0 = (p0 == c.x) && (c.x > THR);
  const bool k1 = (p1 == c.y) && (c.y > THR);
  const bool k2 = (p2 == c.z) && (c.z > THR);
  const bool k3 = (p3 == c.w) && (c.w > THR);

  float4 kv, cv;
  kv.x = k0 ? 1.0f : 0.0f; kv.y = k1 ? 1.0f : 0.0f;
  kv.z = k2 ? 1.0f : 0.0f; kv.w = k3 ? 1.0f : 0.0f;
  cv.x = k0 ? c.x : 0.0f;  cv.y = k1 ? c.y : 0.0f;
  cv.z = k2 ? c.z : 0.0f;  cv.w = k3 ? c.w : 0.0f;

  const size_t o = img_off + (size_t)y * IMG_W + x0;
  *(float4*)(kp_out + o)   = kv;
  *(float4*)(conf_out + o) = cv;
}

extern "C" void kernel_launch(void* const* d_in, const int* in_sizes, int n_in,
                              void* d_out, int out_size, void* d_ws, size_t ws_size,
                              hipStream_t stream) {
  const float* in = (const float*)d_in[0];
  float* out = (float*)d_out;
  const size_t plane = (size_t)NBATCH * IMG_H * IMG_W;  // 33554432
  float* kp_out = out;
  float* conf_out = out + plane;
  const int nblocks = NBATCH * IMG_H;  // 32768
  keypoint_kernel<<<nblocks, 256, 0, stream>>>(in, kp_out, conf_out);
}